// Round 2
// baseline (208.875 us; speedup 1.0000x reference)
//
#include <hip/hip_runtime.h>

// SFM recurrent model via MFMA: B=2048, T=60, D=6, H=64, F=10, O=1.
//
// R1-R3: VALU readlane-GEMV, 183 us. R4: MFMA split-bf16 -> 100 us.
// R5-R11: 78-111 us band. R12: transposed GEMM (A = U^T static,
//   16/16 rows/cols used), 73 us/dispatch. MfmaUtil 13%, VALU 36%,
//   Occ 20% -> latency-bound, 1 blk/CU, barriers serialize.
// R13 FAILED (128 us): __launch_bounds__(512,4) acted as CUDA-style
//   min-BLOCKS/CU -> 8 waves/EU -> VGPR cap 64 -> A-frags spilled to
//   scratch (WRITE_SIZE 8KB -> 17.4MB, reloads inside the 60-step
//   serial loop). Geometry hypothesis never tested.
// R14: same NB=4 / 512-block geometry, __launch_bounds__(512,2):
//   cap >= 128 under either semantics; natural ~76 VGPR fits, no
//   spill; 29KB LDS x2 < 160KB -> 2 blocks/CU resident. Two
//   independent barrier domains per CU: while block A drains a
//   barrier / P-chain, block B issues MFMA.
//
// Layouts (guide-verified): A[m=lane&15][k=quad*8+j]; B[k=quad*8+j]
// [n=lane&15]; C col=lane&15 (n), row=quad*4+reg (m=hcol-in-tile).
// Cols 0-3 = h_hi(b0..3), 8-11 = h_lo(b0..3); cols 4-7/12-15 unused
// (zero h rows / duplicate x rows -> finite garbage, outputs ignored).

#define BB 2048
#define TT 60
#define DD 6
#define HH 64
#define FF 10
#define NB 4      // batches per block

#define XS 968    // xsp per-batch stride in shorts (60*16 + 8 pad)
#define HSK 72    // hsp2 row stride in shorts (16 rows: 0-3 hi(b), 8-11 lo(b))
#define ZC 68     // zt hcol stride in floats (pad 64->68: banks spread)

typedef short bf16x8 __attribute__((ext_vector_type(8)));
typedef float f32x4  __attribute__((ext_vector_type(4)));

__device__ __forceinline__ unsigned short f2bf(float f) {
    union { float f; unsigned u; } v; v.f = f;
    unsigned r = v.u + 0x7fffu + ((v.u >> 16) & 1u);   // RNE
    return (unsigned short)(r >> 16);
}
__device__ __forceinline__ float bf2f(unsigned short b) {
    union { unsigned u; float f; } v; v.u = ((unsigned)b) << 16; return v.f;
}
__device__ __forceinline__ float hsig_f(float v) {
    return __builtin_amdgcn_fmed3f(fmaf(v, 0.16666666666666666f, 0.5f), 0.0f, 1.0f);
}
__device__ __forceinline__ float tanh_f(float x) {
    float xc = fminf(fmaxf(x, -12.0f), 12.0f);
    float e  = __builtin_amdgcn_exp2f(xc * 2.8853900817779268f); // 2*log2(e)
    return (e - 1.0f) * __builtin_amdgcn_rcpf(e + 1.0f);
}
__device__ __forceinline__ float uni(float v) {
    return __int_as_float(__builtin_amdgcn_readfirstlane(__float_as_int(v)));
}
__device__ __forceinline__ void pinv(bf16x8& v) { asm volatile("" : "+v"(v)); }

__global__ __launch_bounds__(512, 2)   // cap>=128 VGPR either semantics; no spill
void sfm_kernel(
    const float* __restrict__ x,
    const float* __restrict__ W_i,  const float* __restrict__ U_i,  const float* __restrict__ b_i,
    const float* __restrict__ W_ste,const float* __restrict__ U_ste,const float* __restrict__ b_ste,
    const float* __restrict__ W_fre,const float* __restrict__ U_fre,const float* __restrict__ b_fre,
    const float* __restrict__ W_c,  const float* __restrict__ U_c,  const float* __restrict__ b_c,
    const float* __restrict__ W_o,  const float* __restrict__ U_o,  const float* __restrict__ b_o,
    const float* __restrict__ U_a,  const float* __restrict__ b_a,
    const float* __restrict__ W_p,  const float* __restrict__ b_p,
    float* __restrict__ out)
{
    const int tid  = threadIdx.x;
    const int lane = tid & 63;
    const int wave = tid >> 6;      // 0..7
    const int q    = lane >> 4;     // quad 0..3
    const int n16  = lane & 15;
    const int b0   = blockIdx.x * NB;

    __shared__ __align__(16) unsigned short xsp[NB * XS];   // presplit x records
    __shared__ __align__(16) unsigned short hsp2[16 * HSK]; // rows 0-3 hhi(b), 8-11 hlo(b)
    __shared__ __align__(16) float zt[4 * 16 * ZC];         // [g][col(part,b)][hcol]
    __shared__ __align__(16) float fb[NB * 12];             // zfre[b][f], parts folded
    __shared__ __align__(16) float ctab[10 * 10 * 2];
    __shared__ float cstabB[10 * 2];
    __shared__ float red[8][8];

    // ---- init 1: stage + pre-split x (one (b,s) record per thread) ----
    if (tid < NB * TT) {
        const float* xg = x + (size_t)b0 * (TT * DD) + tid * DD;
        const int b = tid / TT, s = tid - b * TT;
        unsigned short* dst = &xsp[b * XS + s * 16];
        #pragma unroll
        for (int d = 0; d < DD; ++d) {
            const float v = xg[d];
            const unsigned short hb = f2bf(v);
            dst[d]     = hb;
            dst[8 + d] = f2bf(v - bf2f(hb));
        }
        dst[6] = 0x3F80; dst[7] = 0;   // k=70 bias row: 1.0 (hi), k=71: 0
        dst[14] = 0; dst[15] = 0;      // lo-part: k=70,71 = 0
    }
    if (tid < 10) {
        const float CTc[10] = { 1.0f,  0.8090169943749475f,  0.30901699437494745f,
                               -0.30901699437494745f, -0.8090169943749475f, -1.0f,
                               -0.8090169943749475f, -0.30901699437494745f,
                                0.30901699437494745f,  0.8090169943749475f };
        const float STc[10] = { 0.0f,  0.5877852522924731f,  0.9510565162951535f,
                                0.9510565162951535f,  0.5877852522924731f,  0.0f,
                               -0.5877852522924731f, -0.9510565162951535f,
                               -0.9510565162951535f, -0.5877852522924731f };
        float cc = 0.0f, ss = 0.0f;
        #pragma unroll
        for (int j = 0; j < 10; ++j) if (tid == j) { cc = CTc[j]; ss = STc[j]; }
        cstabB[tid * 2] = cc; cstabB[tid * 2 + 1] = ss;
    }
    for (int i = tid; i < 16 * HSK; i += 512) hsp2[i] = 0;   // h = 0 (hi & lo)
    __syncthreads();
    if (tid < 100) {
        const int mm = tid / 10, ff = tid - mm * 10;
        const int idx = (ff * mm) % 10;
        ctab[tid * 2]     = cstabB[idx * 2];
        ctab[tid * 2 + 1] = cstabB[idx * 2 + 1];
    }

    // ---- A-frags (STATIC, U^T orientation): wave w owns gate tiles
    //      gt=2w, 2w+1 (g=gt>>2, mt=gt&3); wave 7 adds fre tile (t=2).
    //      A[m=n16][k = c*32 + q*8 + j]; k: 0-63 U, 64-69 W, 70 bias. ----
    const int NTILE = (wave == 7) ? 3 : 2;
    bf16x8 Ah[3][3], Al[3][3];
    #pragma unroll
    for (int t = 0; t < 3; ++t) {
        if (t >= NTILE) continue;
        const bool isfre = (wave == 7 && t == 2);
        const int gt = 2 * wave + t;
        const int g  = gt >> 2, mt = gt & 3;
        const int col = mt * 16 + n16;
        const float* Ug = (g == 0) ? U_i : (g == 1) ? U_ste : (g == 2) ? U_c : U_o;
        const float* Wg = (g == 0) ? W_i : (g == 1) ? W_ste : (g == 2) ? W_c : W_o;
        const float* bg = (g == 0) ? b_i : (g == 1) ? b_ste : (g == 2) ? b_c : b_o;
        #pragma unroll
        for (int c = 0; c < 3; ++c) {
            #pragma unroll
            for (int j = 0; j < 8; ++j) {
                const int kv = c * 32 + q * 8 + j;
                float v = 0.0f;
                if (!isfre) {
                    if      (kv < 64)  v = Ug[kv * HH + col];
                    else if (kv < 70)  v = Wg[(kv - 64) * HH + col];
                    else if (kv == 70) v = bg[col];
                } else if (n16 < FF) {
                    if      (kv < 64)  v = U_fre[kv * FF + n16];
                    else if (kv < 70)  v = W_fre[(kv - 64) * FF + n16];
                    else if (kv == 70) v = b_fre[n16];
                }
                const unsigned short hb = f2bf(v);
                Ah[t][c][j] = (short)hb;
                Al[t][c][j] = (short)f2bf(v - bf2f(hb));
            }
            pinv(Ah[t][c]); pinv(Al[t][c]);
        }
    }

    // ---- pointwise consts: pb = tid&3, pc = tid>>2 (0..63), tid<256 active ----
    const int pb = tid & 3;
    const int pc = (tid >> 2) & 63;
    const bool pact = (tid < NB * HH);    // 256 P-active threads (waves 0-3)
    const float bav = b_a[pc];
    const float wpv = W_p[pc];
    const float bpv = uni(b_p[0]);
    float uav[FF];
    #pragma unroll
    for (int f = 0; f < FF; ++f) uav[f] = uni(U_a[f]);

    float Sre[FF], Sim[FF];
    #pragma unroll
    for (int f = 0; f < FF; ++f) { Sre[f] = 0.0f; Sim[f] = 0.0f; }
    float hv = 0.0f;

    // B-frag addresses (dynamic h + x record).
    // Cols 4-7/12-15 are unused outputs: point their x record at batch
    // n16&3 (finite data, ignored); their h rows stay zero from init.
    const unsigned short* hrp = &hsp2[n16 * HSK];
    const unsigned short* xrp = &xsp[(n16 & 3) * XS + (n16 >> 3) * 8];

    __syncthreads();

    int m = 1;  // (s+1) % 10
    for (int s = 0; s < TT; ++s) {
        // ---- B-frags: h chunks (all lanes), x chunk (q0 rows 64-71) ----
        const bf16x8 B0 = *(const bf16x8*)&hrp[q * 8];
        const bf16x8 B1 = *(const bf16x8*)&hrp[32 + q * 8];
        const bf16x8 xv = *(const bf16x8*)&xrp[s * 16];
        const bf16x8 zf = {0, 0, 0, 0, 0, 0, 0, 0};
        const bf16x8 B2 = (q == 0) ? xv : zf;

        // ---- MFMAs: per tile 6 chained (Ah,B)(Al,B) x 3 chunks ----
        f32x4 acc[3];
        #pragma unroll
        for (int t = 0; t < 3; ++t) {
            if (t >= NTILE) continue;
            f32x4 a = {0.0f, 0.0f, 0.0f, 0.0f};
            a = __builtin_amdgcn_mfma_f32_16x16x32_bf16(Ah[t][0], B0, a, 0, 0, 0);
            a = __builtin_amdgcn_mfma_f32_16x16x32_bf16(Al[t][0], B0, a, 0, 0, 0);
            a = __builtin_amdgcn_mfma_f32_16x16x32_bf16(Ah[t][1], B1, a, 0, 0, 0);
            a = __builtin_amdgcn_mfma_f32_16x16x32_bf16(Al[t][1], B1, a, 0, 0, 0);
            a = __builtin_amdgcn_mfma_f32_16x16x32_bf16(Ah[t][2], B2, a, 0, 0, 0);
            a = __builtin_amdgcn_mfma_f32_16x16x32_bf16(Al[t][2], B2, a, 0, 0, 0);
            acc[t] = a;
        }

        // ---- write z: lane (n16=col, q) holds hcols mt*16+q*4..+3 ----
        #pragma unroll
        for (int t = 0; t < 2; ++t) {
            const int gt = 2 * wave + t;
            const int g  = gt >> 2, mt = gt & 3;
            *(f32x4*)&zt[(g * 16 + n16) * ZC + mt * 16 + q * 4] = acc[t];
        }
        if (wave == 7) {   // fre: fold parts (col b + col b+8) via shfl, write fb[b][f]
            f32x4 af;
            #pragma unroll
            for (int r = 0; r < 4; ++r)
                af[r] = acc[2][r] + __shfl_xor(acc[2][r], 8, 64);
            if (n16 < NB) {   // only batches 0..NB-1 (fb is NB*12 floats!)
                #pragma unroll
                for (int r = 0; r < 4; ++r) {
                    const int f = q * 4 + r;
                    if (f < FF) fb[n16 * 12 + f] = af[r];
                }
            }
        }
        __syncthreads();

        // ---- P: batch pb, col pc; z = hi-col + lo-col (full product) ----
        if (pact) {
            const float zi = zt[(0 * 16 + pb) * ZC + pc] + zt[(0 * 16 + pb + 8) * ZC + pc];
            const float zs = zt[(1 * 16 + pb) * ZC + pc] + zt[(1 * 16 + pb + 8) * ZC + pc];
            const float zc = zt[(2 * 16 + pb) * ZC + pc] + zt[(2 * 16 + pb + 8) * ZC + pc];
            const float zo = zt[(3 * 16 + pb) * ZC + pc] + zt[(3 * 16 + pb + 8) * ZC + pc];

            float fr[FF];
            #pragma unroll
            for (int f = 0; f < FF; ++f) fr[f] = hsig_f(fb[pb * 12 + f]);

            const float iv  = hsig_f(zi);
            const float stv = hsig_f(zs);
            const float ov  = hsig_f(zo);
            const float cv  = iv * tanh_f(zc);

            const float* tp = &ctab[m * 20];
            float aacc0 = bav, aacc1 = 0.0f;
            #pragma unroll
            for (int f = 0; f < FF; ++f) {
                const float2 tv = *(const float2*)&tp[f * 2];
                const float fc = stv * fr[f];
                Sre[f] = fmaf(fc, Sre[f], cv * tv.x);
                Sim[f] = fmaf(fc, Sim[f], cv * tv.y);
                const float A = fmaf(Sim[f], Sim[f], Sre[f] * Sre[f]);
                if (f & 1) aacc1 = fmaf(A, uav[f], aacc1);
                else       aacc0 = fmaf(A, uav[f], aacc0);
            }
            hv = ov * tanh_f(aacc0 + aacc1);

            // split h -> bf16 hi/lo rows (the ONLY conversion point)
            {
                const unsigned short hb = f2bf(hv);
                hsp2[pb * HSK + pc]       = hb;
                hsp2[(8 + pb) * HSK + pc] = f2bf(hv - bf2f(hb));
            }
        }
        if (++m == 10) m = 0;
        __syncthreads();
    }

    // ---- output: out[b] = sum_col h*W_p + b_p ----
    // P lane bits: pb = lane&3, pc-in-wave = lane>>2 -> fold bits 2..5
    float val = pact ? hv * wpv : 0.0f;
    val += __shfl_xor(val, 4, 64);
    val += __shfl_xor(val, 8, 64);
    val += __shfl_xor(val, 16, 64);
    val += __shfl_xor(val, 32, 64);
    if (wave < 4 && lane < 4) red[wave][lane] = val;
    __syncthreads();
    if (tid < NB) {
        float acc = bpv;
        #pragma unroll
        for (int w = 0; w < 4; ++w) acc += red[w][tid];
        out[b0 + tid] = acc;
    }
}

extern "C" void kernel_launch(void* const* d_in, const int* in_sizes, int n_in,
                              void* d_out, int out_size, void* d_ws, size_t ws_size,
                              hipStream_t stream) {
    (void)in_sizes; (void)n_in; (void)d_ws; (void)ws_size; (void)out_size;
    const float* x     = (const float*)d_in[0];
    const float* W_i   = (const float*)d_in[1];
    const float* U_i   = (const float*)d_in[2];
    const float* b_i   = (const float*)d_in[3];
    const float* W_ste = (const float*)d_in[4];
    const float* U_ste = (const float*)d_in[5];
    const float* b_ste = (const float*)d_in[6];
    const float* W_fre = (const float*)d_in[7];
    const float* U_fre = (const float*)d_in[8];
    const float* b_fre = (const float*)d_in[9];
    const float* W_c   = (const float*)d_in[10];
    const float* U_c   = (const float*)d_in[11];
    const float* b_c   = (const float*)d_in[12];
    const float* W_o   = (const float*)d_in[13];
    const float* U_o   = (const float*)d_in[14];
    const float* b_o   = (const float*)d_in[15];
    const float* U_a   = (const float*)d_in[16];
    const float* b_a   = (const float*)d_in[17];
    const float* W_p   = (const float*)d_in[18];
    const float* b_p   = (const float*)d_in[19];

    sfm_kernel<<<BB / NB, 512, 0, stream>>>(
        x, W_i, U_i, b_i, W_ste, U_ste, b_ste, W_fre, U_fre, b_fre,
        W_c, U_c, b_c, W_o, U_o, b_o, U_a, b_a, W_p, b_p, (float*)d_out);
}

// Round 3
// 165.215 us; speedup vs baseline: 1.2643x; 1.2643x over previous
//
#include <hip/hip_runtime.h>

// SFM recurrent model via MFMA: B=2048, T=60, D=6, H=64, F=10, O=1.
//
// R1-R11: 78-183 us. R12: transposed GEMM (A=U^T static), NB=8,
//   256 blocks x 512 thr, 73 us. Latency-bound: MfmaUtil 13%, VALU 36%.
// R13 FAILED (128us): launch_bounds(512,4) -> VGPR cap 64 -> spill.
// R14 FAILED (143us): NB=4/512 blocks; 2nd block/CU never co-resident
//   (occ 22%, dur exactly 2x R12). Lesson: per-block step time is the
//   same at NB=4 and NB=8 -> step is latency-bound, multi-block axis
//   dead. Revert geometry; cut the intra-step serial path instead.
// R15: (a) ctab ELIMINATED: rotated phasor T(f,t)=S*e^{-i th f t};
//   T = fc*R_f*T + cv with R_f=e^{-i 2pi f/10} = compile-time const;
//   A=|T|^2 unchanged. -10 LDS reads/thread/step. (b) hi/lo parts
//   folded in M-phase via shfl_xor(8): zt halves, P reads 4 not 8.
//   (c) fb reads vectorized (3 loads not 10). (d) 6-deep MFMA chain
//   split into 2x 3-deep (accH/accL). P-phase LDS: 28 -> 7 reads.
//
// Layouts (guide-verified): A[m=lane&15][k=quad*8+j]; B[k=quad*8+j]
// [n=lane&15]; C col=lane&15 (n), row=quad*4+reg (m=hcol-in-tile).
// B cols 0-7 = h_hi(b0..7), 8-15 = h_lo(b0..7).

#define BB 2048
#define TT 60
#define DD 6
#define HH 64
#define FF 10
#define NB 8      // batches per block

#define XS 968    // xsp per-batch stride in shorts (60*16 + 8 pad)
#define HSK 72    // hsp2 row stride in shorts (16 rows: 0-7 hi(b), 8-15 lo(b))
#define ZC 68     // zt hcol stride in floats (pad 64->68: banks spread)

typedef short bf16x8 __attribute__((ext_vector_type(8)));
typedef float f32x4  __attribute__((ext_vector_type(4)));

__device__ __forceinline__ unsigned short f2bf(float f) {
    union { float f; unsigned u; } v; v.f = f;
    unsigned r = v.u + 0x7fffu + ((v.u >> 16) & 1u);   // RNE
    return (unsigned short)(r >> 16);
}
__device__ __forceinline__ float bf2f(unsigned short b) {
    union { unsigned u; float f; } v; v.u = ((unsigned)b) << 16; return v.f;
}
__device__ __forceinline__ float hsig_f(float v) {
    return __builtin_amdgcn_fmed3f(fmaf(v, 0.16666666666666666f, 0.5f), 0.0f, 1.0f);
}
__device__ __forceinline__ float tanh_f(float x) {
    float xc = fminf(fmaxf(x, -12.0f), 12.0f);
    float e  = __builtin_amdgcn_exp2f(xc * 2.8853900817779268f); // 2*log2(e)
    return (e - 1.0f) * __builtin_amdgcn_rcpf(e + 1.0f);
}
__device__ __forceinline__ float uni(float v) {
    return __int_as_float(__builtin_amdgcn_readfirstlane(__float_as_int(v)));
}
__device__ __forceinline__ void pinv(bf16x8& v) { asm volatile("" : "+v"(v)); }

__global__ __launch_bounds__(512, 1)
void sfm_kernel(
    const float* __restrict__ x,
    const float* __restrict__ W_i,  const float* __restrict__ U_i,  const float* __restrict__ b_i,
    const float* __restrict__ W_ste,const float* __restrict__ U_ste,const float* __restrict__ b_ste,
    const float* __restrict__ W_fre,const float* __restrict__ U_fre,const float* __restrict__ b_fre,
    const float* __restrict__ W_c,  const float* __restrict__ U_c,  const float* __restrict__ b_c,
    const float* __restrict__ W_o,  const float* __restrict__ U_o,  const float* __restrict__ b_o,
    const float* __restrict__ U_a,  const float* __restrict__ b_a,
    const float* __restrict__ W_p,  const float* __restrict__ b_p,
    float* __restrict__ out)
{
    const int tid  = threadIdx.x;
    const int lane = tid & 63;
    const int wave = tid >> 6;      // 0..7
    const int q    = lane >> 4;     // quad 0..3
    const int n16  = lane & 15;
    const int b0   = blockIdx.x * NB;

    __shared__ __align__(16) unsigned short xsp[NB * XS];   // presplit x records
    __shared__ __align__(16) unsigned short hsp2[16 * HSK]; // rows 0-7 hhi(b), 8-15 hlo(b)
    __shared__ __align__(16) float zt[4 * 8 * ZC];          // [g][b][hcol], parts folded
    __shared__ __align__(16) float fb[NB * 12];             // zfre[b][f], parts folded
    __shared__ float red[8][8];

    // ---- init: stage + pre-split x (one (b,s) record per thread) ----
    if (tid < NB * TT) {
        const float* xg = x + (size_t)b0 * (TT * DD) + tid * DD;
        const int b = tid / TT, s = tid - b * TT;
        unsigned short* dst = &xsp[b * XS + s * 16];
        #pragma unroll
        for (int d = 0; d < DD; ++d) {
            const float v = xg[d];
            const unsigned short hb = f2bf(v);
            dst[d]     = hb;
            dst[8 + d] = f2bf(v - bf2f(hb));
        }
        dst[6] = 0x3F80; dst[7] = 0;   // k=70 bias row: 1.0 (hi), k=71: 0
        dst[14] = 0; dst[15] = 0;      // lo-part: k=70,71 = 0
    }
    for (int i = tid; i < 16 * HSK; i += 512) hsp2[i] = 0;   // h = 0 (hi & lo)

    // ---- A-frags (STATIC, U^T orientation): wave w owns gate tiles
    //      gt=2w, 2w+1 (g=gt>>2, mt=gt&3); wave 7 adds fre tile (t=2).
    //      A[m=n16][k = c*32 + q*8 + j]; k: 0-63 U, 64-69 W, 70 bias. ----
    const int NTILE = (wave == 7) ? 3 : 2;
    bf16x8 Ah[3][3], Al[3][3];
    #pragma unroll
    for (int t = 0; t < 3; ++t) {
        if (t >= NTILE) continue;
        const bool isfre = (wave == 7 && t == 2);
        const int gt = 2 * wave + t;
        const int g  = gt >> 2, mt = gt & 3;
        const int col = mt * 16 + n16;
        const float* Ug = (g == 0) ? U_i : (g == 1) ? U_ste : (g == 2) ? U_c : U_o;
        const float* Wg = (g == 0) ? W_i : (g == 1) ? W_ste : (g == 2) ? W_c : W_o;
        const float* bg = (g == 0) ? b_i : (g == 1) ? b_ste : (g == 2) ? b_c : b_o;
        #pragma unroll
        for (int c = 0; c < 3; ++c) {
            #pragma unroll
            for (int j = 0; j < 8; ++j) {
                const int kv = c * 32 + q * 8 + j;
                float v = 0.0f;
                if (!isfre) {
                    if      (kv < 64)  v = Ug[kv * HH + col];
                    else if (kv < 70)  v = Wg[(kv - 64) * HH + col];
                    else if (kv == 70) v = bg[col];
                } else if (n16 < FF) {
                    if      (kv < 64)  v = U_fre[kv * FF + n16];
                    else if (kv < 70)  v = W_fre[(kv - 64) * FF + n16];
                    else if (kv == 70) v = b_fre[n16];
                }
                const unsigned short hb = f2bf(v);
                Ah[t][c][j] = (short)hb;
                Al[t][c][j] = (short)f2bf(v - bf2f(hb));
            }
            pinv(Ah[t][c]); pinv(Al[t][c]);
        }
    }

    // ---- pointwise consts: pb = tid&7 (batch), pc = tid>>3 (hcol) ----
    const int pb = tid & 7;
    const int pc = tid >> 3;       // 0..63
    const float bav = b_a[pc];
    const float wpv = W_p[pc];
    const float bpv = uni(b_p[0]);
    float uav[FF];
    #pragma unroll
    for (int f = 0; f < FF; ++f) uav[f] = uni(U_a[f]);

    // Rotated-phasor state: T(f,t) = S(f,t) * e^{-i*2pi*f*t/10}.
    // Recurrence T = fc * R_f * T + cv, R_f = e^{-i*2pi*f/10} (constant).
    // A = |S|^2 = |T|^2. Rotators (compile-time folded in unrolled loop):
    const float CRT[10] = { 1.0f,  0.8090169943749475f,  0.30901699437494745f,
                           -0.30901699437494745f, -0.8090169943749475f, -1.0f,
                           -0.8090169943749475f, -0.30901699437494745f,
                            0.30901699437494745f,  0.8090169943749475f };
    const float SRT[10] = { 0.0f,  0.5877852522924731f,  0.9510565162951535f,
                            0.9510565162951535f,  0.5877852522924731f,  0.0f,
                           -0.5877852522924731f, -0.9510565162951535f,
                           -0.9510565162951535f, -0.5877852522924731f };

    float Tre[FF], Tim[FF];
    #pragma unroll
    for (int f = 0; f < FF; ++f) { Tre[f] = 0.0f; Tim[f] = 0.0f; }
    float hv = 0.0f;

    // B-frag addresses (dynamic h + x record)
    const unsigned short* hrp = &hsp2[n16 * HSK];
    const unsigned short* xrp = &xsp[(n16 & 7) * XS + (n16 >> 3) * 8];

    __syncthreads();

    for (int s = 0; s < TT; ++s) {
        // ---- B-frags: h chunks (all lanes), x chunk (q0 rows 64-71) ----
        const bf16x8 B0 = *(const bf16x8*)&hrp[q * 8];
        const bf16x8 B1 = *(const bf16x8*)&hrp[32 + q * 8];
        const bf16x8 xv = *(const bf16x8*)&xrp[s * 16];
        const bf16x8 zf = {0, 0, 0, 0, 0, 0, 0, 0};
        const bf16x8 B2 = (q == 0) ? xv : zf;

        // ---- MFMAs: per tile two independent 3-chains (Ah | Al), sum ----
        f32x4 acc[3];
        #pragma unroll
        for (int t = 0; t < 3; ++t) {
            if (t >= NTILE) continue;
            f32x4 aH = {0.0f, 0.0f, 0.0f, 0.0f};
            f32x4 aL = {0.0f, 0.0f, 0.0f, 0.0f};
            aH = __builtin_amdgcn_mfma_f32_16x16x32_bf16(Ah[t][0], B0, aH, 0, 0, 0);
            aL = __builtin_amdgcn_mfma_f32_16x16x32_bf16(Al[t][0], B0, aL, 0, 0, 0);
            aH = __builtin_amdgcn_mfma_f32_16x16x32_bf16(Ah[t][1], B1, aH, 0, 0, 0);
            aL = __builtin_amdgcn_mfma_f32_16x16x32_bf16(Al[t][1], B1, aL, 0, 0, 0);
            aH = __builtin_amdgcn_mfma_f32_16x16x32_bf16(Ah[t][2], B2, aH, 0, 0, 0);
            aL = __builtin_amdgcn_mfma_f32_16x16x32_bf16(Al[t][2], B2, aL, 0, 0, 0);
            acc[t] = aH + aL;
        }

        // ---- fold hi+lo part cols (n16 ^ 8) in-register, write zt ----
        #pragma unroll
        for (int t = 0; t < 2; ++t) {
            const int gt = 2 * wave + t;
            const int g  = gt >> 2, mt = gt & 3;
            f32x4 af;
            #pragma unroll
            for (int r = 0; r < 4; ++r)
                af[r] = acc[t][r] + __shfl_xor(acc[t][r], 8, 64);
            if (n16 < 8)
                *(f32x4*)&zt[(g * 8 + n16) * ZC + mt * 16 + q * 4] = af;
        }
        if (wave == 7) {   // fre: fold parts, write fb[b][f]
            f32x4 af;
            #pragma unroll
            for (int r = 0; r < 4; ++r)
                af[r] = acc[2][r] + __shfl_xor(acc[2][r], 8, 64);
            if (n16 < 8) {
                #pragma unroll
                for (int r = 0; r < 4; ++r) {
                    const int f = q * 4 + r;
                    if (f < FF) fb[n16 * 12 + f] = af[r];
                }
            }
        }
        __syncthreads();

        // ---- P: batch pb, col pc; z already part-folded ----
        const float zi = zt[(0 * 8 + pb) * ZC + pc];
        const float zs = zt[(1 * 8 + pb) * ZC + pc];
        const float zc = zt[(2 * 8 + pb) * ZC + pc];
        const float zo = zt[(3 * 8 + pb) * ZC + pc];

        const float4 fb0 = *(const float4*)&fb[pb * 12];
        const float4 fb1 = *(const float4*)&fb[pb * 12 + 4];
        const float2 fb2 = *(const float2*)&fb[pb * 12 + 8];
        float fr[FF];
        fr[0] = hsig_f(fb0.x); fr[1] = hsig_f(fb0.y);
        fr[2] = hsig_f(fb0.z); fr[3] = hsig_f(fb0.w);
        fr[4] = hsig_f(fb1.x); fr[5] = hsig_f(fb1.y);
        fr[6] = hsig_f(fb1.z); fr[7] = hsig_f(fb1.w);
        fr[8] = hsig_f(fb2.x); fr[9] = hsig_f(fb2.y);

        const float iv  = hsig_f(zi);
        const float stv = hsig_f(zs);
        const float ov  = hsig_f(zo);
        const float cv  = iv * tanh_f(zc);

        float aacc0 = bav, aacc1 = 0.0f;
        #pragma unroll
        for (int f = 0; f < FF; ++f) {
            const float fc = stv * fr[f];
            // T' = fc * (R_f * T) + cv,  R_f = cos - i sin
            const float tre = fmaf(SRT[f], Tim[f],  CRT[f] * Tre[f]);
            const float tim = fmaf(CRT[f], Tim[f], -SRT[f] * Tre[f]);
            Tre[f] = fmaf(fc, tre, cv);
            Tim[f] = fc * tim;
            const float A = fmaf(Tim[f], Tim[f], Tre[f] * Tre[f]);
            if (f & 1) aacc1 = fmaf(A, uav[f], aacc1);
            else       aacc0 = fmaf(A, uav[f], aacc0);
        }
        hv = ov * tanh_f(aacc0 + aacc1);

        // split h -> bf16 hi/lo rows (the ONLY conversion point)
        {
            const unsigned short hb = f2bf(hv);
            hsp2[pb * HSK + pc]       = hb;
            hsp2[(8 + pb) * HSK + pc] = f2bf(hv - bf2f(hb));
        }
        __syncthreads();
    }

    // ---- output: out[b] = sum_col h*W_p + b_p ----
    // P lane bits: pb = lane&7, pc-in-wave = lane>>3 -> fold bits 3..5
    float val = hv * wpv;
    val += __shfl_xor(val, 8, 64);
    val += __shfl_xor(val, 16, 64);
    val += __shfl_xor(val, 32, 64);
    if (lane < 8) red[wave][lane] = val;
    __syncthreads();
    if (tid < NB) {
        float acc = bpv;
        #pragma unroll
        for (int w = 0; w < 8; ++w) acc += red[w][tid];
        out[b0 + tid] = acc;
    }
}

extern "C" void kernel_launch(void* const* d_in, const int* in_sizes, int n_in,
                              void* d_out, int out_size, void* d_ws, size_t ws_size,
                              hipStream_t stream) {
    (void)in_sizes; (void)n_in; (void)d_ws; (void)ws_size; (void)out_size;
    const float* x     = (const float*)d_in[0];
    const float* W_i   = (const float*)d_in[1];
    const float* U_i   = (const float*)d_in[2];
    const float* b_i   = (const float*)d_in[3];
    const float* W_ste = (const float*)d_in[4];
    const float* U_ste = (const float*)d_in[5];
    const float* b_ste = (const float*)d_in[6];
    const float* W_fre = (const float*)d_in[7];
    const float* U_fre = (const float*)d_in[8];
    const float* b_fre = (const float*)d_in[9];
    const float* W_c   = (const float*)d_in[10];
    const float* U_c   = (const float*)d_in[11];
    const float* b_c   = (const float*)d_in[12];
    const float* W_o   = (const float*)d_in[13];
    const float* U_o   = (const float*)d_in[14];
    const float* b_o   = (const float*)d_in[15];
    const float* U_a   = (const float*)d_in[16];
    const float* b_a   = (const float*)d_in[17];
    const float* W_p   = (const float*)d_in[18];
    const float* b_p   = (const float*)d_in[19];

    sfm_kernel<<<BB / NB, 512, 0, stream>>>(
        x, W_i, U_i, b_i, W_ste, U_ste, b_ste, W_fre, U_fre, b_fre,
        W_c, U_c, b_c, W_o, U_o, b_o, U_a, b_a, W_p, b_p, (float*)d_out);
}